// Round 9
// baseline (2620.506 us; speedup 1.0000x reference)
//
#include <hip/hip_runtime.h>
#include <cstdint>

#define NN 25000
#define NE 300000

typedef unsigned short ushort_t;
typedef __attribute__((ext_vector_type(8))) short bf16x8;
typedef __attribute__((ext_vector_type(4))) float f32x4;
typedef __attribute__((ext_vector_type(4))) unsigned short u16x4;
typedef __attribute__((ext_vector_type(8))) unsigned short u16x8;

__device__ __forceinline__ float4 ld4(const float* p){ return *reinterpret_cast<const float4*>(p); }
__device__ __forceinline__ void st4(float* p, const float4& v){ *reinterpret_cast<float4*>(p) = v; }
__device__ __forceinline__ float bf2f(ushort_t u){ return __uint_as_float((unsigned)u << 16); }
__device__ __forceinline__ ushort_t f2bfu(float f){
  unsigned x = __float_as_uint(f);
  return (ushort_t)((x + 0x7fffu + ((x >> 16) & 1u)) >> 16);   // RNE
}
// 16-lane-group butterfly sum (lanes sharing l>>4)
__device__ __forceinline__ float rsum16(float s) {
  s += __shfl_xor(s, 1); s += __shfl_xor(s, 2);
  s += __shfl_xor(s, 4); s += __shfl_xor(s, 8);
  return s;
}

// fixed-point (2^32): order-independent integer accumulation -> deterministic
#define FXS 4294967296.0
#define FXI 2.3283064365386963e-10
__device__ __forceinline__ long long f2fx(float v) {
  return (long long)llrint((double)v * FXS);
}
__device__ __forceinline__ float fx2f(long long q) { return (float)((double)q * FXI); }

#define MFMA(a, b, c) __builtin_amdgcn_mfma_f32_16x16x32_bf16((a), (b), (c), 0, 0, 0)

// ---------- weight convert+transpose: dst[mat][n][k] = bf16(src[mat][k][n]) ----------
__global__ __launch_bounds__(256)
void wconv_k(const float* __restrict__ src, ushort_t* __restrict__ dst,
             int K, int N, int total)
{
  int i = blockIdx.x * 256 + threadIdx.x;
  if (i >= total) return;
  int kn = K * N;
  int mat = i / kn, r = i - mat * kn;
  int n = r / K, k = r - n * K;
  dst[i] = f2bfu(src[(size_t)mat * kn + (size_t)k * N + n]);
}

// ---------- gathers ----------
__global__ __launch_bounds__(256)
void gather_h_k(const float* __restrict__ tab, const int* __restrict__ idx,
                float* __restrict__ hf, ushort_t* __restrict__ hb)
{
  int t = blockIdx.x * 256 + threadIdx.x;
  if (t >= NN * 32) return;
  int i = t >> 5, c4 = t & 31;
  float4 v = ld4(tab + (size_t)idx[i] * 128 + c4 * 4);
  st4(hf + (size_t)i * 128 + c4 * 4, v);
  u16x4 b = { f2bfu(v.x), f2bfu(v.y), f2bfu(v.z), f2bfu(v.w) };
  *reinterpret_cast<u16x4*>(hb + (size_t)i * 128 + c4 * 4) = b;
}

__global__ __launch_bounds__(256)
void gather_e_k(const float* __restrict__ tab, const int* __restrict__ idx,
                ushort_t* __restrict__ eb)
{
  int t = blockIdx.x * 256 + threadIdx.x;
  if (t >= NE * 32) return;
  int i = t >> 5, c4 = t & 31;
  float4 v = ld4(tab + (size_t)idx[i] * 128 + c4 * 4);
  u16x4 b = { f2bfu(v.x), f2bfu(v.y), f2bfu(v.z), f2bfu(v.w) };
  *reinterpret_cast<u16x4*>(eb + (size_t)i * 128 + c4 * 4) = b;
}

// ---------- CSR build (per call; graph shared by all 4 layers) ----------
__global__ __launch_bounds__(256)
void count_k(const int* __restrict__ dst, int* __restrict__ counts)
{
  int e = blockIdx.x * 256 + threadIdx.x;
  if (e < NE) atomicAdd(&counts[dst[e]], 1);
}

__global__ __launch_bounds__(1024)
void scan_k(const int* __restrict__ counts, int* __restrict__ start,
            int* __restrict__ cursor)
{
  __shared__ int part[1024];
  const int t = threadIdx.x;
  const int base = t * 25;
  int loc[25];
  int s = 0;
#pragma unroll
  for (int i = 0; i < 25; ++i) {
    int n = base + i;
    int c = (n < NN) ? counts[n] : 0;
    loc[i] = s; s += c;
  }
  part[t] = s;
  __syncthreads();
  for (int off = 1; off < 1024; off <<= 1) {
    int v = (t >= off) ? part[t - off] : 0;
    __syncthreads();
    part[t] += v;
    __syncthreads();
  }
  int excl = (t == 0) ? 0 : part[t - 1];
#pragma unroll
  for (int i = 0; i < 25; ++i) {
    int n = base + i;
    if (n < NN) { int v = excl + loc[i]; start[n] = v; cursor[n] = v; }
  }
  if (t == 0) start[NN] = NE;
}

__global__ __launch_bounds__(256)
void scatter_k(const int* __restrict__ src, const int* __restrict__ dst,
               int* __restrict__ cursor, int2* __restrict__ csr_es)
{
  int e = blockIdx.x * 256 + threadIdx.x;
  if (e >= NE) return;
  int pos = atomicAdd(&cursor[dst[e]], 1);    // order nondet; reduce is order-indep
  csr_es[pos] = make_int2(e, src[e]);
}

// ---------- MFMA GEMM: [M,K]@[K,N]; coalesced repack stores; opt bias+resid+LN ----
// used for QKV (osep) and O_h (LN epilogue). 70KB LDS -> 2 blocks/CU.
__global__ __launch_bounds__(256)
void gemmN_bf_k(const ushort_t* __restrict__ A, const ushort_t* __restrict__ WT,
                const int K, const int M, const int ldo,
                const float* __restrict__ Bias, const int osep,
                const float* __restrict__ ResF, const ushort_t* __restrict__ ResB,
                const float* __restrict__ G, const float* __restrict__ Bb,
                ushort_t* __restrict__ OutB, float* __restrict__ OutF)
{
  __shared__ __align__(16) ushort_t SM[2 * 128 * 136];
  __shared__ float mu[128], rs[128];
  ushort_t* Xs = SM;
  ushort_t* Ws = SM + 128 * 136;
  const int tid = threadIdx.x;
  const int m0 = blockIdx.x * 128;
  const int col0 = blockIdx.y * 128;

  const int l = tid & 63, wv = tid >> 6;
  const int lr = l & 15, lk = l >> 4;
  const int mb = (wv & 1) * 64, nb = (wv >> 1) * 64;
  f32x4 acc[4][4];
  const f32x4 zf = {0.f, 0.f, 0.f, 0.f};
#pragma unroll
  for (int mi = 0; mi < 4; ++mi)
#pragma unroll
    for (int ni = 0; ni < 4; ++ni) acc[mi][ni] = zf;

  for (int kc = 0; kc < K; kc += 128) {
    if (kc) __syncthreads();
    for (int c = tid; c < 2048; c += 256) {
      int r = c >> 4, k8 = c & 15;
      bf16x8 v = {};
      if (m0 + r < M)
        v = *reinterpret_cast<const bf16x8*>(A + (size_t)(m0 + r) * K + kc + k8 * 8);
      *reinterpret_cast<bf16x8*>(Xs + r * 136 + k8 * 8) = v;
    }
    for (int c = tid; c < 2048; c += 256) {
      int r = c >> 4, k8 = c & 15;
      *reinterpret_cast<bf16x8*>(Ws + r * 136 + k8 * 8) =
          *reinterpret_cast<const bf16x8*>(WT + (size_t)(col0 + r) * K + kc + k8 * 8);
    }
    __syncthreads();
#pragma unroll
    for (int kt = 0; kt < 4; ++kt) {
      bf16x8 af[4], bw[4];
#pragma unroll
      for (int i = 0; i < 4; ++i)
        af[i] = *reinterpret_cast<const bf16x8*>(Xs + (mb + i * 16 + lr) * 136 + kt * 32 + lk * 8);
#pragma unroll
      for (int i = 0; i < 4; ++i)
        bw[i] = *reinterpret_cast<const bf16x8*>(Ws + (nb + i * 16 + lr) * 136 + kt * 32 + lk * 8);
#pragma unroll
      for (int mi = 0; mi < 4; ++mi)
#pragma unroll
        for (int ni = 0; ni < 4; ++ni)
          acc[mi][ni] = MFMA(af[mi], bw[ni], acc[mi][ni]);
    }
  }

  if (G == nullptr) {
    __syncthreads();
    ushort_t* Rb = SM;
#pragma unroll
    for (int mi = 0; mi < 4; ++mi)
#pragma unroll
      for (int rr = 0; rr < 4; ++rr) {
        int row = mb + mi * 16 + lk * 4 + rr;
#pragma unroll
        for (int ni = 0; ni < 4; ++ni) {
          int col = nb + ni * 16 + lr;
          float v = acc[mi][ni][rr];
          if (Bias) v = fmaxf(v + Bias[col0 + col], 0.f);
          Rb[row * 136 + col] = f2bfu(v);
        }
      }
    __syncthreads();
    ushort_t* ob = OutB + (osep ? (size_t)blockIdx.y * M * 128 : (size_t)col0);
    for (int c = tid; c < 2048; c += 256) {
      int r = c >> 4, k8 = c & 15;
      if (m0 + r < M)
        *reinterpret_cast<u16x8*>(ob + (size_t)(m0 + r) * ldo + k8 * 8) =
            *reinterpret_cast<u16x8*>(Rb + r * 136 + k8 * 8);
    }
    return;
  }

  // LN epilogue
  __syncthreads();
  float* Tf = reinterpret_cast<float*>(SM);
#pragma unroll
  for (int mi = 0; mi < 4; ++mi)
#pragma unroll
    for (int rr = 0; rr < 4; ++rr) {
      int row = mb + mi * 16 + lk * 4 + rr;
      int grow = m0 + row;
#pragma unroll
      for (int ni = 0; ni < 4; ++ni) {
        int col = nb + ni * 16 + lr;
        float t = acc[mi][ni][rr] + Bias[col];
        if (grow < M)
          t += ResF ? ResF[(size_t)grow * 128 + col] : bf2f(ResB[(size_t)grow * 128 + col]);
        Tf[row * 132 + col] = t;
      }
    }
  __syncthreads();
  {
    int r = tid >> 1, jj = tid & 1;
    const float* tp = Tf + r * 132 + jj * 64;
    float s = 0.f;
    for (int c2 = 0; c2 < 64; ++c2) s += tp[c2];
    s += __shfl_xor(s, 1);
    float mean = s * (1.f / 128.f);
    float v = 0.f;
    for (int c2 = 0; c2 < 64; ++c2) { float d = tp[c2] - mean; v += d * d; }
    v += __shfl_xor(v, 1);
    if (jj == 0) { mu[r] = mean; rs[r] = 1.f / sqrtf(v * (1.f / 128.f) + 1e-5f); }
  }
  __syncthreads();
  for (int c = tid; c < 4096; c += 256) {
    int r = c >> 5, c4 = c & 31;
    int grow = m0 + r;
    if (grow >= M) continue;
    float4 t = ld4(Tf + r * 132 + c4 * 4);
    float4 gv = ld4(G + c4 * 4), bv = ld4(Bb + c4 * 4);
    float m = mu[r], ir = rs[r];
    float o0 = gv.x * (t.x - m) * ir + bv.x;
    float o1 = gv.y * (t.y - m) * ir + bv.y;
    float o2 = gv.z * (t.z - m) * ir + bv.z;
    float o3 = gv.w * (t.w - m) * ir + bv.w;
    u16x4 ub = { f2bfu(o0), f2bfu(o1), f2bfu(o2), f2bfu(o3) };
    *reinterpret_cast<u16x4*>(OutB + (size_t)grow * 128 + c4 * 4) = ub;
    if (OutF) st4(OutF + (size_t)grow * 128 + c4 * 4, make_float4(o0, o1, o2, o3));
  }
}

// ---------- fused h-FFN (unchanged from round 8) ----------
__global__ __launch_bounds__(256)
void ffn_f_k(const ushort_t* __restrict__ Xbf, const float* __restrict__ ResF,
             const ushort_t* __restrict__ W1T, const float* __restrict__ B1,
             const ushort_t* __restrict__ W2T, const float* __restrict__ B2,
             const float* __restrict__ G, const float* __restrict__ Bb,
             ushort_t* __restrict__ OutB, float* __restrict__ OutF, int M)
{
  __shared__ __align__(16) ushort_t SM[8704 + 8704 + 17408];
  __shared__ float mu[64], rs[64];
  ushort_t* Xs   = SM;
  ushort_t* Mid0 = SM + 8704;
  ushort_t* Wst  = SM + 17408;
  const int tid = threadIdx.x;
  const int m0 = blockIdx.x * 64;
  const int l = tid & 63, wv = tid >> 6, lr = l & 15, lk = l >> 4;
  const f32x4 zf = {0.f, 0.f, 0.f, 0.f};

  for (int c = tid; c < 1024; c += 256) {
    int r = c >> 4, k8 = c & 15;
    bf16x8 v = {};
    if (m0 + r < M) v = *reinterpret_cast<const bf16x8*>(Xbf + (size_t)(m0 + r) * 128 + k8 * 8);
    *reinterpret_cast<bf16x8*>(Xs + r * 136 + k8 * 8) = v;
  }
  for (int c = tid; c < 2048; c += 256) {
    int r = c >> 4, k8 = c & 15;
    *reinterpret_cast<bf16x8*>(Wst + r * 136 + k8 * 8) =
        *reinterpret_cast<const bf16x8*>(W1T + (size_t)r * 128 + k8 * 8);
  }
  __syncthreads();

  f32x4 acc2[8];
#pragma unroll
  for (int i = 0; i < 8; ++i) acc2[i] = zf;
  ushort_t rsv[8][4];

  {
    f32x4 a1[8];
#pragma unroll
    for (int i = 0; i < 8; ++i) a1[i] = zf;
#pragma unroll
    for (int kt = 0; kt < 4; ++kt) {
      bf16x8 af = *reinterpret_cast<const bf16x8*>(Xs + (wv * 16 + lr) * 136 + kt * 32 + lk * 8);
#pragma unroll
      for (int ni = 0; ni < 8; ++ni) {
        bf16x8 bw = *reinterpret_cast<const bf16x8*>(Wst + (ni * 16 + lr) * 136 + kt * 32 + lk * 8);
        a1[ni] = MFMA(af, bw, a1[ni]);
      }
    }
#pragma unroll
    for (int ni = 0; ni < 8; ++ni)
#pragma unroll
      for (int rr = 0; rr < 4; ++rr)
        Mid0[(wv * 16 + lk * 4 + rr) * 136 + ni * 16 + lr] =
            f2bfu(fmaxf(a1[ni][rr] + B1[ni * 16 + lr], 0.f));
  }
  __syncthreads();
  for (int c = tid; c < 2048; c += 256) {
    int r = c >> 4, k8 = c & 15;
    *reinterpret_cast<bf16x8*>(Wst + r * 136 + k8 * 8) =
        *reinterpret_cast<const bf16x8*>(W1T + (size_t)(128 + r) * 128 + k8 * 8);
  }
  __syncthreads();
  {
    f32x4 a1[8];
#pragma unroll
    for (int i = 0; i < 8; ++i) a1[i] = zf;
#pragma unroll
    for (int kt = 0; kt < 4; ++kt) {
      bf16x8 af = *reinterpret_cast<const bf16x8*>(Xs + (wv * 16 + lr) * 136 + kt * 32 + lk * 8);
#pragma unroll
      for (int ni = 0; ni < 8; ++ni) {
        bf16x8 bw = *reinterpret_cast<const bf16x8*>(Wst + (ni * 16 + lr) * 136 + kt * 32 + lk * 8);
        a1[ni] = MFMA(af, bw, a1[ni]);
      }
    }
    __syncthreads();
    if (!ResF) {
#pragma unroll
      for (int ni = 0; ni < 8; ++ni)
#pragma unroll
        for (int rr = 0; rr < 4; ++rr)
          rsv[ni][rr] = Xs[(wv * 16 + lk * 4 + rr) * 136 + ni * 16 + lr];
    }
#pragma unroll
    for (int ni = 0; ni < 8; ++ni)
#pragma unroll
      for (int rr = 0; rr < 4; ++rr)
        Xs[(wv * 16 + lk * 4 + rr) * 136 + ni * 16 + lr] =
            f2bfu(fmaxf(a1[ni][rr] + B1[128 + ni * 16 + lr], 0.f));
  }
  __syncthreads();
  for (int c = tid; c < 2048; c += 256) {
    int r = c >> 4, k8 = c & 15;
    *reinterpret_cast<bf16x8*>(Wst + r * 136 + k8 * 8) =
        *reinterpret_cast<const bf16x8*>(W2T + (size_t)r * 256 + k8 * 8);
  }
  __syncthreads();
#pragma unroll
  for (int kt = 0; kt < 4; ++kt) {
    bf16x8 af = *reinterpret_cast<const bf16x8*>(Mid0 + (wv * 16 + lr) * 136 + kt * 32 + lk * 8);
#pragma unroll
    for (int ni = 0; ni < 8; ++ni) {
      bf16x8 bw = *reinterpret_cast<const bf16x8*>(Wst + (ni * 16 + lr) * 136 + kt * 32 + lk * 8);
      acc2[ni] = MFMA(af, bw, acc2[ni]);
    }
  }
  __syncthreads();
  for (int c = tid; c < 2048; c += 256) {
    int r = c >> 4, k8 = c & 15;
    *reinterpret_cast<bf16x8*>(Wst + r * 136 + k8 * 8) =
        *reinterpret_cast<const bf16x8*>(W2T + (size_t)r * 256 + 128 + k8 * 8);
  }
  __syncthreads();
#pragma unroll
  for (int kt = 0; kt < 4; ++kt) {
    bf16x8 af = *reinterpret_cast<const bf16x8*>(Xs + (wv * 16 + lr) * 136 + kt * 32 + lk * 8);
#pragma unroll
    for (int ni = 0; ni < 8; ++ni) {
      bf16x8 bw = *reinterpret_cast<const bf16x8*>(Wst + (ni * 16 + lr) * 136 + kt * 32 + lk * 8);
      acc2[ni] = MFMA(af, bw, acc2[ni]);
    }
  }
  __syncthreads();
  float* Tf = reinterpret_cast<float*>(Wst);
#pragma unroll
  for (int ni = 0; ni < 8; ++ni)
#pragma unroll
    for (int rr = 0; rr < 4; ++rr) {
      int row = wv * 16 + lk * 4 + rr;
      int grow = m0 + row;
      int col = ni * 16 + lr;
      float t = acc2[ni][rr] + B2[col];
      if (ResF) { if (grow < M) t += ResF[(size_t)grow * 128 + col]; }
      else      t += bf2f(rsv[ni][rr]);
      Tf[row * 132 + col] = t;
    }
  __syncthreads();
  {
    int r = tid >> 2, jj = tid & 3;
    const float* tp = Tf + r * 132 + jj * 32;
    float s = 0.f;
    for (int c2 = 0; c2 < 32; ++c2) s += tp[c2];
    s += __shfl_xor(s, 1); s += __shfl_xor(s, 2);
    float mean = s * (1.f / 128.f);
    float v = 0.f;
    for (int c2 = 0; c2 < 32; ++c2) { float d = tp[c2] - mean; v += d * d; }
    v += __shfl_xor(v, 1); v += __shfl_xor(v, 2);
    if (jj == 0) { mu[r] = mean; rs[r] = 1.f / sqrtf(v * (1.f / 128.f) + 1e-5f); }
  }
  __syncthreads();
  for (int c = tid; c < 2048; c += 256) {
    int r = c >> 5, c4 = c & 31;
    int grow = m0 + r;
    if (grow >= M) continue;
    float4 t = ld4(Tf + r * 132 + c4 * 4);
    float4 gv = ld4(G + c4 * 4), bv = ld4(Bb + c4 * 4);
    float m = mu[r], ir = rs[r];
    float o0 = gv.x * (t.x - m) * ir + bv.x;
    float o1 = gv.y * (t.y - m) * ir + bv.y;
    float o2 = gv.z * (t.z - m) * ir + bv.z;
    float o3 = gv.w * (t.w - m) * ir + bv.w;
    u16x4 ub = { f2bfu(o0), f2bfu(o1), f2bfu(o2), f2bfu(o3) };
    *reinterpret_cast<u16x4*>(OutB + (size_t)grow * 128 + c4 * 4) = ub;
    if (OutF) st4(OutF + (size_t)grow * 128 + c4 * 4, make_float4(o0, o1, o2, o3));
  }
}

// ---------- e-side mega-fusion v2: barrier-free after staging ----------
// 64 e-rows/block, 4 waves; each wave owns rows wv*16..wv*16+15 for EVERY phase
// (A-frags, outputs, score, LN) -> only 1 __syncthreads (after e staging).
// Weights read directly from global (L1/L2-hot; same 32KB tile for all blocks).
// LN via in-register row stats + 16-lane shuffle. LDS = Es + Mid0 = 34.8KB
// -> 4 blocks/CU. Phase order FFN1a->FFN2a->FFN1b->FFN2b keeps e1 in Es for resid.
__global__ __launch_bounds__(256)
void efused_k(ushort_t* __restrict__ Ebuf,
              const ushort_t* __restrict__ Qb, const ushort_t* __restrict__ Kb,
              const int* __restrict__ src, const int* __restrict__ dst,
              float* __restrict__ wbuf,
              const ushort_t* __restrict__ weT,
              const ushort_t* __restrict__ owT, const float* __restrict__ oBias,
              const float* __restrict__ G1, const float* __restrict__ B1n,
              const ushort_t* __restrict__ W1T, const float* __restrict__ fB1,
              const ushort_t* __restrict__ W2T, const float* __restrict__ fB2,
              const float* __restrict__ G2, const float* __restrict__ B2n,
              int M)
{
  __shared__ __align__(16) ushort_t Es[64 * 136];
  __shared__ __align__(16) ushort_t Mid0[64 * 136];
  const int tid = threadIdx.x;
  const int m0 = blockIdx.x * 64;
  const int l = tid & 63, wv = tid >> 6, lr = l & 15, lk = l >> 4;
  const f32x4 zf = {0.f, 0.f, 0.f, 0.f};
  const int arow = (wv * 16 + lr) * 136;        // A-fragment row base (this wave)
  const int orow0 = (wv * 16 + lk * 4) * 136;   // output row base (this lane)

  // P1: stage e tile (cross-wave) — the only barrier
  for (int c = tid; c < 1024; c += 256) {
    int r = c >> 4, k8 = c & 15;
    bf16x8 v = {};
    if (m0 + r < M) v = *reinterpret_cast<const bf16x8*>(Ebuf + (size_t)(m0 + r) * 128 + k8 * 8);
    *reinterpret_cast<bf16x8*>(Es + r * 136 + k8 * 8) = v;
  }
  __syncthreads();

  // P2: pe = Es @ weT -> Mid0 (wave-local rows)
  {
    f32x4 a1[8];
#pragma unroll
    for (int i = 0; i < 8; ++i) a1[i] = zf;
#pragma unroll
    for (int kt = 0; kt < 4; ++kt) {
      bf16x8 af = *reinterpret_cast<const bf16x8*>(Es + arow + kt * 32 + lk * 8);
#pragma unroll
      for (int ni = 0; ni < 8; ++ni) {
        bf16x8 bw = *reinterpret_cast<const bf16x8*>(weT + (size_t)(ni * 16 + lr) * 128 + kt * 32 + lk * 8);
        a1[ni] = MFMA(af, bw, a1[ni]);
      }
    }
#pragma unroll
    for (int ni = 0; ni < 8; ++ni)
#pragma unroll
      for (int rr = 0; rr < 4; ++rr)
        Mid0[orow0 + rr * 136 + ni * 16 + lr] = f2bfu(a1[ni][rr]);
  }

  // P3: score in place on Mid0 (wave-local rows): sc = K[src]*Q[dst]*0.25*pe
#pragma unroll
  for (int it = 0; it < 4; ++it) {
    int r = wv * 16 + it * 4 + lk;
    int e = m0 + r;
    if (e < M) {
      int j = lr;
      int s = src[e], d = dst[e];
      u16x8 kv = *reinterpret_cast<const u16x8*>(Kb + (size_t)s * 128 + j * 8);
      u16x8 qv = *reinterpret_cast<const u16x8*>(Qb + (size_t)d * 128 + j * 8);
      u16x8 pv = *reinterpret_cast<const u16x8*>(Mid0 + r * 136 + j * 8);
      float hsum = 0.f;
      u16x8 ob;
#pragma unroll
      for (int i = 0; i < 8; ++i) {
        float x = bf2f(kv[i]) * bf2f(qv[i]) * 0.25f * bf2f(pv[i]);
        hsum += x; ob[i] = f2bfu(x);
      }
      *reinterpret_cast<u16x8*>(Mid0 + r * 136 + j * 8) = ob;
      hsum += __shfl_xor(hsum, 1);   // pair lane l^1: same row, head partner
      float w = expf(fminf(fmaxf(hsum, -5.f), 5.f));
      if ((j & 1) == 0) wbuf[(size_t)e * 8 + (j >> 1)] = w;
    }
  }

  // P4: O_e = sc @ owT; t = +bias+resid(Es); LN1 in-register; e1 -> Es
  {
    f32x4 a1[8];
#pragma unroll
    for (int i = 0; i < 8; ++i) a1[i] = zf;
#pragma unroll
    for (int kt = 0; kt < 4; ++kt) {
      bf16x8 af = *reinterpret_cast<const bf16x8*>(Mid0 + arow + kt * 32 + lk * 8);
#pragma unroll
      for (int ni = 0; ni < 8; ++ni) {
        bf16x8 bw = *reinterpret_cast<const bf16x8*>(owT + (size_t)(ni * 16 + lr) * 128 + kt * 32 + lk * 8);
        a1[ni] = MFMA(af, bw, a1[ni]);
      }
    }
    float t[8][4];
#pragma unroll
    for (int ni = 0; ni < 8; ++ni) {
      int col = ni * 16 + lr;
      float bb = oBias[col];
#pragma unroll
      for (int rr = 0; rr < 4; ++rr)
        t[ni][rr] = a1[ni][rr] + bb + bf2f(Es[orow0 + rr * 136 + col]);
    }
#pragma unroll
    for (int rr = 0; rr < 4; ++rr) {
      float s = 0.f;
#pragma unroll
      for (int ni = 0; ni < 8; ++ni) s += t[ni][rr];
      float mean = rsum16(s) * (1.f / 128.f);
      float v = 0.f;
#pragma unroll
      for (int ni = 0; ni < 8; ++ni) { float d = t[ni][rr] - mean; v += d * d; }
      float ir = 1.f / sqrtf(rsum16(v) * (1.f / 128.f) + 1e-5f);
#pragma unroll
      for (int ni = 0; ni < 8; ++ni) {
        int col = ni * 16 + lr;
        Es[orow0 + rr * 136 + col] =
            f2bfu(G1[col] * (t[ni][rr] - mean) * ir + B1n[col]);
      }
    }
  }

  // FFN1a: Mid0 = relu(e1 @ W1[:,0:128] + fB1[0:128])
  {
    f32x4 a1[8];
#pragma unroll
    for (int i = 0; i < 8; ++i) a1[i] = zf;
#pragma unroll
    for (int kt = 0; kt < 4; ++kt) {
      bf16x8 af = *reinterpret_cast<const bf16x8*>(Es + arow + kt * 32 + lk * 8);
#pragma unroll
      for (int ni = 0; ni < 8; ++ni) {
        bf16x8 bw = *reinterpret_cast<const bf16x8*>(W1T + (size_t)(ni * 16 + lr) * 128 + kt * 32 + lk * 8);
        a1[ni] = MFMA(af, bw, a1[ni]);
      }
    }
#pragma unroll
    for (int ni = 0; ni < 8; ++ni)
#pragma unroll
      for (int rr = 0; rr < 4; ++rr)
        Mid0[orow0 + rr * 136 + ni * 16 + lr] =
            f2bfu(fmaxf(a1[ni][rr] + fB1[ni * 16 + lr], 0.f));
  }

  f32x4 acc2[8];
#pragma unroll
  for (int i = 0; i < 8; ++i) acc2[i] = zf;

  // FFN2a: acc2 = Mid0 @ W2[0:128,:]  (frees Mid0 for Mid1)
#pragma unroll
  for (int kt = 0; kt < 4; ++kt) {
    bf16x8 af = *reinterpret_cast<const bf16x8*>(Mid0 + arow + kt * 32 + lk * 8);
#pragma unroll
    for (int ni = 0; ni < 8; ++ni) {
      bf16x8 bw = *reinterpret_cast<const bf16x8*>(W2T + (size_t)(ni * 16 + lr) * 256 + kt * 32 + lk * 8);
      acc2[ni] = MFMA(af, bw, acc2[ni]);
    }
  }

  // FFN1b: Mid1 = relu(e1 @ W1[:,128:256] + fB1[128:256]) -> Mid0 (Es keeps e1)
  {
    f32x4 a1[8];
#pragma unroll
    for (int i = 0; i < 8; ++i) a1[i] = zf;
#pragma unroll
    for (int kt = 0; kt < 4; ++kt) {
      bf16x8 af = *reinterpret_cast<const bf16x8*>(Es + arow + kt * 32 + lk * 8);
#pragma unroll
      for (int ni = 0; ni < 8; ++ni) {
        bf16x8 bw = *reinterpret_cast<const bf16x8*>(W1T + (size_t)(128 + ni * 16 + lr) * 128 + kt * 32 + lk * 8);
        a1[ni] = MFMA(af, bw, a1[ni]);
      }
    }
#pragma unroll
    for (int ni = 0; ni < 8; ++ni)
#pragma unroll
      for (int rr = 0; rr < 4; ++rr)
        Mid0[orow0 + rr * 136 + ni * 16 + lr] =
            f2bfu(fmaxf(a1[ni][rr] + fB1[128 + ni * 16 + lr], 0.f));
  }

  // FFN2b: acc2 += Mid1 @ W2[128:256,:]
#pragma unroll
  for (int kt = 0; kt < 4; ++kt) {
    bf16x8 af = *reinterpret_cast<const bf16x8*>(Mid0 + arow + kt * 32 + lk * 8);
#pragma unroll
    for (int ni = 0; ni < 8; ++ni) {
      bf16x8 bw = *reinterpret_cast<const bf16x8*>(W2T + (size_t)(ni * 16 + lr) * 256 + 128 + kt * 32 + lk * 8);
      acc2[ni] = MFMA(af, bw, acc2[ni]);
    }
  }

  // LN2 in-register (resid = e1 from Es); repack e2 through Mid0 -> coalesced store
  {
    float t[8][4];
#pragma unroll
    for (int ni = 0; ni < 8; ++ni) {
      int col = ni * 16 + lr;
      float bb = fB2[col];
#pragma unroll
      for (int rr = 0; rr < 4; ++rr)
        t[ni][rr] = acc2[ni][rr] + bb + bf2f(Es[orow0 + rr * 136 + col]);
    }
#pragma unroll
    for (int rr = 0; rr < 4; ++rr) {
      float s = 0.f;
#pragma unroll
      for (int ni = 0; ni < 8; ++ni) s += t[ni][rr];
      float mean = rsum16(s) * (1.f / 128.f);
      float v = 0.f;
#pragma unroll
      for (int ni = 0; ni < 8; ++ni) { float d = t[ni][rr] - mean; v += d * d; }
      float ir = 1.f / sqrtf(rsum16(v) * (1.f / 128.f) + 1e-5f);
#pragma unroll
      for (int ni = 0; ni < 8; ++ni) {
        int col = ni * 16 + lr;
        Mid0[orow0 + rr * 136 + col] =
            f2bfu(G2[col] * (t[ni][rr] - mean) * ir + B2n[col]);
      }
    }
#pragma unroll
    for (int it = 0; it < 4; ++it) {
      int r = wv * 16 + it * 4 + lk;
      if (m0 + r < M)
        *reinterpret_cast<u16x8*>(Ebuf + (size_t)(m0 + r) * 128 + lr * 8) =
            *reinterpret_cast<u16x8*>(Mid0 + r * 136 + lr * 8);
    }
  }
}

// ---------- CSR gather-reduce ----------
__global__ __launch_bounds__(256)
void reduce_k(const ushort_t* __restrict__ V, const float* __restrict__ wbuf,
              const int* __restrict__ start, const int2* __restrict__ csr_es,
              ushort_t* __restrict__ out)
{
  int t = blockIdx.x * 256 + threadIdx.x;
  int n = t >> 4;
  if (n >= NN) return;
  int j = t & 15;
  int p0 = start[n], p1 = start[n + 1];
  long long acc[8] = {};
  long long zacc = 0;
  for (int p = p0; p < p1; ++p) {
    int2 es = csr_es[p];
    float w = wbuf[(size_t)es.x * 8 + (j >> 1)];
    u16x8 vv = *reinterpret_cast<const u16x8*>(V + (size_t)es.y * 128 + j * 8);
    zacc += f2fx(w);
#pragma unroll
    for (int i = 0; i < 8; ++i) acc[i] += f2fx(bf2f(vv[i]) * w);
  }
  float zz = fx2f(zacc) + 1e-6f;
  u16x8 ob;
#pragma unroll
  for (int i = 0; i < 8; ++i) ob[i] = f2bfu(fx2f(acc[i]) / zz);
  *reinterpret_cast<u16x8*>(out + (size_t)n * 128 + j * 8) = ob;
}

// ---------- per-graph mean over 1000 nodes ----------
__global__ __launch_bounds__(256)
void graphmean_k(const float* __restrict__ h, float* __restrict__ hg)
{
  __shared__ float red[256];
  int g = blockIdx.x, tid = threadIdx.x;
  int c = tid & 127, half = tid >> 7;
  float s = 0.f;
  for (int r = half; r < 1000; r += 2) s += h[(size_t)(g * 1000 + r) * 128 + c];
  red[tid] = s;
  __syncthreads();
  if (half == 0) hg[g * 128 + c] = (red[c] + red[c + 128]) / 1000.0f;
}

// ---------- readout MLP: 128 -> 64 -> 32 -> 1 ----------
__global__ __launch_bounds__(256)
void readout_k(const float* __restrict__ hg,
               const float* __restrict__ w0, const float* __restrict__ b0,
               const float* __restrict__ w1, const float* __restrict__ b1,
               const float* __restrict__ w2, const float* __restrict__ b2,
               float* __restrict__ out)
{
  __shared__ float hs[25 * 128];
  __shared__ float t0[25 * 64];
  __shared__ float t1[25 * 32];
  int tid = threadIdx.x;
  for (int i = tid; i < 25 * 128; i += 256) hs[i] = hg[i];
  __syncthreads();
  for (int i = tid; i < 25 * 64; i += 256) {
    int r = i >> 6, c = i & 63;
    float a = b0[c];
    for (int k = 0; k < 128; k++) a += hs[r * 128 + k] * w0[k * 64 + c];
    t0[i] = fmaxf(a, 0.f);
  }
  __syncthreads();
  for (int i = tid; i < 25 * 32; i += 256) {
    int r = i >> 5, c = i & 31;
    float a = b1[c];
    for (int k = 0; k < 64; k++) a += t0[r * 64 + k] * w1[k * 32 + c];
    t1[i] = fmaxf(a, 0.f);
  }
  __syncthreads();
  if (tid < 25) {
    float a = b2[0];
    for (int k = 0; k < 32; k++) a += t1[tid * 32 + k] * w2[k];
    out[tid] = a;
  }
}

extern "C" void kernel_launch(void* const* d_in, const int* in_sizes, int n_in,
                              void* d_out, int out_size, void* d_ws, size_t ws_size,
                              hipStream_t stream)
{
  const float* emb_h  = (const float*)d_in[0];
  const float* emb_e  = (const float*)d_in[1];
  const float* w_qkve = (const float*)d_in[2];
  const float* o_w    = (const float*)d_in[3];
  const float* o_b    = (const float*)d_in[4];
  const float* ln_s   = (const float*)d_in[5];
  const float* ln_b   = (const float*)d_in[6];
  const float* ffn_w1 = (const float*)d_in[7];
  const float* ffn_b1 = (const float*)d_in[8];
  const float* ffn_w2 = (const float*)d_in[9];
  const float* ffn_b2 = (const float*)d_in[10];
  const float* mlp_w0 = (const float*)d_in[11];
  const float* mlp_b0 = (const float*)d_in[12];
  const float* mlp_w1 = (const float*)d_in[13];
  const float* mlp_b1 = (const float*)d_in[14];
  const float* mlp_w2 = (const float*)d_in[15];
  const float* mlp_b2 = (const float*)d_in[16];
  const int* tokens = (const int*)d_in[17];
  const int* etype  = (const int*)d_in[18];
  const int* src    = (const int*)d_in[19];
  const int* dst    = (const int*)d_in[20];

  // ---- workspace (~142 MB) ----
  char* ws = (char*)d_ws;
  size_t off = 0;
  auto alloc = [&](size_t bytes) { char* p = ws + off; off += bytes; return p; };
  int2*      csr_es = (int2*)alloc((size_t)NE * 8);
  float*     h      = (float*)alloc((size_t)NN * 128 * 4);
  float*     hg     = (float*)alloc(25 * 128 * 4);
  float*     wbuf   = (float*)alloc((size_t)NE * 8 * 4);
  int*       counts = (int*)alloc((size_t)NN * 4);
  int*       cursor = (int*)alloc((size_t)NN * 4);
  int*       startp = (int*)alloc((size_t)(NN + 1) * 4);
  ushort_t*  h_bf   = (ushort_t*)alloc((size_t)NN * 128 * 2);
  ushort_t*  ha_bf  = (ushort_t*)alloc((size_t)NN * 128 * 2);
  ushort_t*  Qb     = (ushort_t*)alloc((size_t)NN * 128 * 2);   // Q,K,V contiguous (osep)
  ushort_t*  Kb     = (ushort_t*)alloc((size_t)NN * 128 * 2);
  ushort_t*  Vb     = (ushort_t*)alloc((size_t)NN * 128 * 2);
  ushort_t*  e_bf   = (ushort_t*)alloc((size_t)NE * 128 * 2);
  ushort_t*  wt     = (ushort_t*)alloc(917504 * 2);

  ushort_t* qkveT = wt;            // 16 mats [128][128]
  ushort_t* owT   = wt + 262144;   // 8 mats  [128][128]
  ushort_t* w1T   = wt + 393216;   // 8 mats  [256][128]
  ushort_t* w2T   = wt + 655360;   // 8 mats  [128][256]
  wconv_k<<<1024, 256, 0, stream>>>(w_qkve, qkveT, 128, 128, 262144);
  wconv_k<<<512,  256, 0, stream>>>(o_w,    owT,   128, 128, 131072);
  wconv_k<<<1024, 256, 0, stream>>>(ffn_w1, w1T,   128, 256, 262144);
  wconv_k<<<1024, 256, 0, stream>>>(ffn_w2, w2T,   256, 128, 262144);

  gather_h_k<<<3125, 256, 0, stream>>>(emb_h, tokens, h, h_bf);
  gather_e_k<<<37500, 256, 0, stream>>>(emb_e, etype, e_bf);

  hipMemsetAsync(counts, 0, (size_t)NN * 4, stream);
  count_k<<<(NE + 255) / 256, 256, 0, stream>>>(dst, counts);
  scan_k<<<1, 1024, 0, stream>>>(counts, startp, cursor);
  scatter_k<<<(NE + 255) / 256, 256, 0, stream>>>(src, dst, cursor, csr_es);

  const int GN = (NN + 127) / 128;    // 196
  const int FN = (NN + 63) / 64;      // 391
  const int FE = (NE + 63) / 64;      // 4688

  for (int l = 0; l < 4; ++l) {
    const ushort_t* qkvT = qkveT + (size_t)l * 4 * 16384;
    const ushort_t* weT  = qkveT + ((size_t)l * 4 + 3) * 16384;
    const ushort_t* ow0T = owT + ((size_t)l * 2 + 0) * 16384;
    const ushort_t* ow1T = owT + ((size_t)l * 2 + 1) * 16384;
    const ushort_t* w1hT = w1T + ((size_t)l * 2 + 0) * 32768;
    const ushort_t* w1eT = w1T + ((size_t)l * 2 + 1) * 32768;
    const ushort_t* w2hT = w2T + ((size_t)l * 2 + 0) * 32768;
    const ushort_t* w2eT = w2T + ((size_t)l * 2 + 1) * 32768;
    const float* ob0 = o_b + ((size_t)l * 2 + 0) * 128;
    const float* ob1 = o_b + ((size_t)l * 2 + 1) * 128;
    const float* ls0 = ln_s + ((size_t)l * 4 + 0) * 128;
    const float* ls1 = ln_s + ((size_t)l * 4 + 1) * 128;
    const float* ls2 = ln_s + ((size_t)l * 4 + 2) * 128;
    const float* ls3 = ln_s + ((size_t)l * 4 + 3) * 128;
    const float* lb0 = ln_b + ((size_t)l * 4 + 0) * 128;
    const float* lb1 = ln_b + ((size_t)l * 4 + 1) * 128;
    const float* lb2 = ln_b + ((size_t)l * 4 + 2) * 128;
    const float* lb3 = ln_b + ((size_t)l * 4 + 3) * 128;
    const float* fb1h = ffn_b1 + ((size_t)l * 2 + 0) * 256;
    const float* fb1e = ffn_b1 + ((size_t)l * 2 + 1) * 256;
    const float* fb2h = ffn_b2 + ((size_t)l * 2 + 0) * 128;
    const float* fb2e = ffn_b2 + ((size_t)l * 2 + 1) * 128;

    // fused QKV projections
    gemmN_bf_k<<<dim3(GN, 3), 256, 0, stream>>>(h_bf, qkvT, 128, NN, 128,
        nullptr, 1, nullptr, nullptr, nullptr, nullptr, Qb, nullptr);

    // e-side mega kernel v2 (barrier-free): pe -> score -> O_e+LN -> FFN+LN
    efused_k<<<FE, 256, 0, stream>>>(e_bf, Qb, Kb, src, dst, wbuf,
        weT, ow1T, ob1, ls1, lb1, w1eT, fb1e, w2eT, fb2e, ls3, lb3, NE);

    // h-side attention + O_h + FFN
    reduce_k<<<1563, 256, 0, stream>>>(Vb, wbuf, startp, csr_es, ha_bf);
    gemmN_bf_k<<<dim3(GN, 1), 256, 0, stream>>>(ha_bf, ow0T, 128, NN, 128,
        ob0, 0, h, nullptr, ls0, lb0, h_bf, h);
    ffn_f_k<<<FN, 256, 0, stream>>>(h_bf, h, w1hT, fb1h, w2hT, fb2h,
                                    ls2, lb2, h_bf, h, NN);
  }

  graphmean_k<<<25, 256, 0, stream>>>(h, hg);
  readout_k<<<1, 256, 0, stream>>>(hg, mlp_w0, mlp_b0, mlp_w1, mlp_b1, mlp_w2, mlp_b2,
                                   (float*)d_out);
}